// Round 1
// 382.252 us; speedup vs baseline: 1.0409x; 1.0409x over previous
//
#include <hip/hip_runtime.h>
#include <hip/hip_bf16.h>

#define N_NODES 100000
#define NPAD 100032                         // 64-row-aligned node count
#define N_EDGES 1600000
#define ETOT (N_EDGES + N_NODES)
#define NFEAT 165
#define KP 192                              // K padded to 32-multiple
#define HID 128
#define NCLS 2
#define NEG 0.2f

// CSR radix-build parameters
#define NBUCK 391                           // ceil(N_NODES/256); bucket = dst >> 8
#define CHUNK 16384
#define NCHUNK 104                          // ceil(ETOT/CHUNK)
#define GS_BLOCKS 2048                      // gat1 grid: 8192 waves = device capacity

typedef short bf16x8 __attribute__((ext_vector_type(8)));
typedef float f32x4 __attribute__((ext_vector_type(4)));
typedef float f32x2 __attribute__((ext_vector_type(2)));

// ---- workspace layout (units of 4 bytes) ----
#define OFF_FLAG 0
#define OFF_W 16
// weight sub-offsets (within wb = ws + OFF_W)
#define WO_ATT1 42496
#define WO_BIAS1 42624
#define WO_W2L 42752
#define WO_B2L 43008
#define WO_W2R 43010
#define WO_B2R 43266
#define WO_ATT2 43268
#define WO_BIAS2 43270

#define OFF_XB   43392
#define OFF_W2A  OFF_XB                     // 16-B-aligned W2l[256]|W2r[256] copy
#define OFF_WT   (OFF_XB + NPAD * KP / 2)   // bf16 WT [256][192]
#define OFF_BCAT (OFF_WT + 256 * KP / 2)    // fp32 bias concat [256]
#define OFF_XLB  (OFF_BCAT + 256)           // bf16 xl rows [NPAD][128]
#define OFF_XRB  (OFF_XLB + NPAD * HID / 2) // bf16 xr rows
#define OFF_PAIRS (OFF_XRB + NPAD * HID / 2) // packed uint pairs[ETOT]
#define OFF_CSR  (OFF_PAIRS + 2 * ETOT)     // csr_src[ETOT]
#define OFF_ROWPTR (OFF_CSR + ETOT)         // rowptr[N_NODES+1]
#define OFF_S    (OFF_ROWPTR + N_NODES + 8) // per-(bucket,chunk) offsets
#define OFF_XL2  (OFF_S + NBUCK * NCHUNK + 8)
#define OFF_XR2  (OFF_XL2 + N_NODES * NCLS)
#define OFF_H    (OFF_XR2 + N_NODES * NCLS) // (unused since gemm2 fusion)
#define OFF_DL   (OFF_H + N_NODES * HID)    // fp32 dl[NPAD] = att1 . xl[n]
#define OFF_DR   (OFF_DL + NPAD)            // fp32 dr[NPAD] = att1 . xr[n]

__device__ __forceinline__ float bload16(unsigned short u) {
    return __uint_as_float(((unsigned)u) << 16);
}

// lrelu(v) = 0.6v + 0.4|v|
__device__ __forceinline__ float lrelu(float v) {
    return fmaf(0.4f, fabsf(v), 0.6f * v);
}

// unpack 8 bf16 (as uint4) into 4 packed f32 pairs {col 2t, col 2t+1}
__device__ __forceinline__ void unpack8p(uint4 q, f32x2* f) {
    f[0][0] = __uint_as_float(q.x << 16); f[0][1] = __uint_as_float(q.x & 0xffff0000u);
    f[1][0] = __uint_as_float(q.y << 16); f[1][1] = __uint_as_float(q.y & 0xffff0000u);
    f[2][0] = __uint_as_float(q.z << 16); f[2][1] = __uint_as_float(q.z & 0xffff0000u);
    f[3][0] = __uint_as_float(q.w << 16); f[3][1] = __uint_as_float(q.w & 0xffff0000u);
}

// packed-f32 VOP3P ops (CDNA: v_pk_add_f32 / v_pk_fma_f32, full rate, 2 lanes of
// f32 per instruction). hipcc will not select these from scalar source.
__device__ __forceinline__ f32x2 pk_add(f32x2 a, f32x2 b) {
    f32x2 d;
    asm("v_pk_add_f32 %0, %1, %2" : "=v"(d) : "v"(a), "v"(b));
    return d;
}
__device__ __forceinline__ void pk_fma_acc(f32x2& acc, f32x2 a, f32x2 b) {
    asm("v_pk_fma_f32 %0, %1, %2, %0" : "+v"(acc) : "v"(a), "v"(b));
}

__device__ __forceinline__ unsigned short f2b(float f) {
    __hip_bfloat16 b = __float2bfloat16(f);
    return *(unsigned short*)&b;
}

__device__ __forceinline__ unsigned pack2(float a, float b) {
    return (unsigned)f2b(a) | ((unsigned)f2b(b) << 16);
}

// wave-uniform dtype sniff: 64 halves of x; bf16 -> ~all plausible, fp32 -> ~58%
__device__ __forceinline__ unsigned detect_flag(const unsigned short* x16, int lane) {
    unsigned short hh = x16[lane];
    unsigned e = (hh >> 7) & 0xFF;
    bool pl = ((hh & 0x7FFF) == 0) || (e >= 100 && e <= 140);
    unsigned long long m = __ballot(pl);
    return (__popcll(m) >= 52) ? 1u : 0u;
}

// ---- fused: per-chunk bucket histogram (blocks 0..NCHUNK-1) + weight prep ----
#define PREP_WT 49152                       // 256*192
#define PREP_BC (PREP_WT + 256)
#define PREP_TOT (PREP_BC + 776)
#define PREP_BLKS ((PREP_TOT + 255) / 256)
__global__ void __launch_bounds__(256) k_prep_hist(
        const int* __restrict__ edst, int* __restrict__ bh,
        const unsigned short* __restrict__ x16,
        const void* W1l, const void* b1l, const void* W1r, const void* b1r,
        const void* att1, const void* bias1, const void* W2l, const void* b2l,
        const void* W2r, const void* b2r, const void* att2, const void* bias2,
        unsigned* __restrict__ flagp, unsigned short* __restrict__ wt,
        float* __restrict__ bcat, float* __restrict__ wb,
        float* __restrict__ w2a) {
    __shared__ int hist[NBUCK];
    if (blockIdx.x < NCHUNK) {
        for (int i = threadIdx.x; i < NBUCK; i += 256) hist[i] = 0;
        __syncthreads();
        int base = blockIdx.x * CHUNK;
        for (int i = threadIdx.x; i < CHUNK; i += 256) {
            int e = base + i;
            if (e >= ETOT) break;
            int d = (e < N_EDGES) ? edst[e] : (e - N_EDGES);
            atomicAdd(&hist[d >> 8], 1);
        }
        __syncthreads();
        for (int b = threadIdx.x; b < NBUCK; b += 256)
            bh[b * NCHUNK + blockIdx.x] = hist[b];
        return;
    }
    // ---- prep part ----
    int lane = threadIdx.x & 63;
    unsigned isbf = detect_flag(x16, lane);
    int i = (blockIdx.x - NCHUNK) * 256 + threadIdx.x;
    if (i == 0) *flagp = isbf;
    if (i >= PREP_TOT) return;
    if (i < PREP_WT) {
        int n = i / KP, k = i - n * KP;
        unsigned short v = 0;
        if (k < NFEAT) {
            const void* src = (n < HID) ? W1l : W1r;
            size_t off = (size_t)k * HID + (n & (HID - 1));
            v = isbf ? ((const unsigned short*)src)[off]
                     : f2b(((const float*)src)[off]);
        }
        wt[i] = v;
    } else if (i < PREP_BC) {
        int n = i - PREP_WT;
        const void* src = (n < HID) ? b1l : b1r;
        int off = n & (HID - 1);
        bcat[n] = isbf ? bload16(((const unsigned short*)src)[off])
                       : ((const float*)src)[off];
    } else {
        int j = i - PREP_BC;
        const void* src; int off; int dst;
        if      (j < 128) { src = att1;  off = j;       dst = WO_ATT1 + j; }
        else if (j < 256) { src = bias1; off = j - 128; dst = WO_BIAS1 + (j - 128); }
        else if (j < 512) { src = W2l;   off = j - 256; dst = WO_W2L + (j - 256); }
        else if (j < 514) { src = b2l;   off = j - 512; dst = WO_B2L + (j - 512); }
        else if (j < 770) { src = W2r;   off = j - 514; dst = WO_W2R + (j - 514); }
        else if (j < 772) { src = b2r;   off = j - 770; dst = WO_B2R + (j - 770); }
        else if (j < 774) { src = att2;  off = j - 772; dst = WO_ATT2 + (j - 772); }
        else              { src = bias2; off = j - 774; dst = WO_BIAS2 + (j - 774); }
        float val = isbf ? bload16(((const unsigned short*)src)[off])
                         : ((const float*)src)[off];
        wb[dst] = val;
        // 16-B-aligned copy of W2l|W2r for the fused layer-2 projection
        if (j >= 256 && j < 512) w2a[j - 256] = val;
        else if (j >= 514 && j < 770) w2a[256 + (j - 514)] = val;
    }
}

// ---- exclusive scan of the NBUCK*NCHUNK counts (uint4-vectorized) ----
__global__ void __launch_bounds__(512) k_pa_scan(int* __restrict__ S,
                                                 int* __restrict__ rowptr) {
    __shared__ int lds[512];
    const int TOT4 = (NBUCK * NCHUNK) / 4;   // 10166, exact
    int t = threadIdx.x;
    int b4 = t * 20;
    uint4* S4 = (uint4*)S;
    int sum = 0;
    for (int k = 0; k < 20; k++) {
        int i = b4 + k;
        if (i < TOT4) {
            uint4 v = S4[i];
            sum += (int)(v.x + v.y + v.z + v.w);
        }
    }
    lds[t] = sum;
    __syncthreads();
    for (int off = 1; off < 512; off <<= 1) {
        int v = lds[t];
        if (t >= off) v += lds[t - off];
        __syncthreads();
        lds[t] = v;
        __syncthreads();
    }
    int carry = (t == 0) ? 0 : lds[t - 1];
    for (int k = 0; k < 20; k++) {
        int i = b4 + k;
        if (i < TOT4) {
            uint4 v = S4[i];
            uint4 o;
            o.x = carry; carry += v.x;
            o.y = carry; carry += v.y;
            o.z = carry; carry += v.z;
            o.w = carry; carry += v.w;
            S4[i] = o;
        }
    }
    if (t == 0) rowptr[N_NODES] = ETOT;
}

// ====== fused: pairs scatter (blocks 0..NCHUNK-1) + layer-1 MFMA GEMM ========
// The scatter (memory/atomic-bound) and GEMM1 (MFMA/LDS-bound) are independent:
// scatter needs only the scanned S; GEMM1 needs only wt/bcat from prep. Fusing
// them into one grid lets the complementary work co-schedule across CUs instead
// of serializing at a kernel boundary.
#define XS_STRIDE 200
__global__ void __launch_bounds__(256) k_scatter_gemm1(
        const int* __restrict__ esrc, const int* __restrict__ edst,
        const int* __restrict__ S, unsigned* __restrict__ pairs,
        const void* __restrict__ x, const unsigned* __restrict__ flagp,
        const unsigned short* __restrict__ wt, const float* __restrict__ bcat,
        const float* __restrict__ attp,
        __hip_bfloat16* __restrict__ xlb, __hip_bfloat16* __restrict__ xrb,
        float* __restrict__ dl, float* __restrict__ dr) {
    __shared__ union {
        struct { unsigned short xs[64 * XS_STRIDE]; float dpart[4][64]; } g;
        int cur[NBUCK];
    } u;

    if (blockIdx.x < NCHUNK) {
        // ---- scatter: pairs entry = src (bits 0..16) | (dst & 255) << 24 ----
        for (int i = threadIdx.x; i < NBUCK; i += 256)
            u.cur[i] = S[i * NCHUNK + blockIdx.x];
        __syncthreads();
        int base = blockIdx.x * CHUNK;
        for (int i = threadIdx.x; i < CHUNK; i += 256) {
            int e = base + i;
            if (e >= ETOT) break;
            int s = (e < N_EDGES) ? esrc[e] : (e - N_EDGES);
            int d = (e < N_EDGES) ? edst[e] : (e - N_EDGES);
            int p = atomicAdd(&u.cur[d >> 8], 1);
            pairs[p] = (unsigned)s | ((unsigned)(d & 255) << 24);
        }
        return;
    }

    // ---- layer-1 GEMM via bf16 MFMA (C^T trick) + att-dot epilogue ----
    int tid = threadIdx.x;
    int wave = tid >> 6, lane = tid & 63;
    int quad = lane >> 4, li = lane & 15;
    int node0 = (blockIdx.x - NCHUNK) * 64;
    unsigned isbf = *flagp;
    const float* xf = (const float*)x;
    const unsigned short* x16 = (const unsigned short*)x;

    // zero pad cols [165,192)
    for (int i = tid; i < 64 * 27; i += 256) {
        int r = i / 27, c = 165 + (i - r * 27);
        u.g.xs[r * XS_STRIDE + c] = 0;
    }
    if (node0 + 64 <= N_NODES) {
        if (isbf) {
            const uint4* src = (const uint4*)(x16 + (size_t)node0 * NFEAT);
            for (int i = tid; i < 1320; i += 256) {   // 1320*8 = 64*165 halves
                uint4 v = src[i];
                int f = i * 8;
                unsigned short hh[8] = {
                    (unsigned short)(v.x & 0xffff), (unsigned short)(v.x >> 16),
                    (unsigned short)(v.y & 0xffff), (unsigned short)(v.y >> 16),
                    (unsigned short)(v.z & 0xffff), (unsigned short)(v.z >> 16),
                    (unsigned short)(v.w & 0xffff), (unsigned short)(v.w >> 16)};
#pragma unroll
                for (int t = 0; t < 8; t++) {
                    int ff = f + t, r = ff / NFEAT, c = ff - r * NFEAT;
                    u.g.xs[r * XS_STRIDE + c] = hh[t];
                }
            }
        } else {
            const float4* src = (const float4*)(xf + (size_t)node0 * NFEAT);
            for (int i = tid; i < 2640; i += 256) {   // 2640*4 = 64*165 floats
                float4 v = src[i];
                int f = i * 4;
                unsigned short hh[4] = {f2b(v.x), f2b(v.y), f2b(v.z), f2b(v.w)};
#pragma unroll
                for (int t = 0; t < 4; t++) {
                    int ff = f + t, r = ff / NFEAT, c = ff - r * NFEAT;
                    u.g.xs[r * XS_STRIDE + c] = hh[t];
                }
            }
        }
    } else {
        for (int i = tid; i < 64 * NFEAT; i += 256) {
            int r = i / NFEAT, c = i - r * NFEAT;
            int grow = node0 + r;
            unsigned short v = 0;
            if (grow < N_NODES) {
                size_t g = (size_t)grow * NFEAT + c;
                v = isbf ? x16[g] : f2b(xf[g]);
            }
            u.g.xs[r * XS_STRIDE + c] = v;
        }
    }

    bf16x8 wfrag[4][6];
#pragma unroll
    for (int q = 0; q < 4; q++) {
        int n = wave * 64 + q * 16 + li;
#pragma unroll
        for (int kk = 0; kk < 6; kk++)
            wfrag[q][kk] = *(const bf16x8*)&wt[(size_t)n * KP + kk * 32 + quad * 8];
    }
    float4 bv[4], attq4[4];
    int colbase = (wave & 1) * 64;
#pragma unroll
    for (int q = 0; q < 4; q++) {
        bv[q] = *(const float4*)&bcat[wave * 64 + q * 16 + quad * 4];
        attq4[q] = *(const float4*)&attp[colbase + q * 16 + quad * 4];
    }
    __syncthreads();

    for (int mt = 0; mt < 4; mt++) {
        bf16x8 xfrag[6];
#pragma unroll
        for (int kk = 0; kk < 6; kk++)
            xfrag[kk] = *(const bf16x8*)&u.g.xs[(mt * 16 + li) * XS_STRIDE + kk * 32 + quad * 8];
        int node = node0 + mt * 16 + li;
        __hip_bfloat16* dst = (wave < 2) ? xlb : xrb;
        float dp = 0.f;
#pragma unroll
        for (int q = 0; q < 4; q++) {
            f32x4 a = {0.f, 0.f, 0.f, 0.f};
#pragma unroll
            for (int kk = 0; kk < 6; kk++)
                a = __builtin_amdgcn_mfma_f32_16x16x32_bf16(wfrag[q][kk], xfrag[kk], a, 0, 0, 0);
            float f0 = a[0] + bv[q].x, f1 = a[1] + bv[q].y;
            float f2 = a[2] + bv[q].z, f3 = a[3] + bv[q].w;
            dp = fmaf(f0, attq4[q].x, dp);
            dp = fmaf(f1, attq4[q].y, dp);
            dp = fmaf(f2, attq4[q].z, dp);
            dp = fmaf(f3, attq4[q].w, dp);
            uint2 val = { pack2(f0, f1), pack2(f2, f3) };
            int col = colbase + q * 16 + quad * 4;
            *(uint2*)&dst[(size_t)node * HID + col] = val;
        }
        dp += __shfl_xor(dp, 16);
        dp += __shfl_xor(dp, 32);
        if (lane < 16) u.g.dpart[wave][mt * 16 + li] = dp;
    }
    __syncthreads();
    if (tid < 64)
        dl[node0 + tid] = u.g.dpart[0][tid] + u.g.dpart[1][tid];
    else if (tid < 128)
        dr[node0 + tid - 64] = u.g.dpart[2][tid - 64] + u.g.dpart[3][tid - 64];
}

__global__ void __launch_bounds__(256) k_bsort(const int* __restrict__ S,
                                               const unsigned* __restrict__ pairs,
                                               int* __restrict__ rowptr,
                                               int* __restrict__ csr) {
    __shared__ int hist[256];
    __shared__ int cur[256];
    int b = blockIdx.x, t = threadIdx.x;
    int beg = S[b * NCHUNK];
    int end = (b == NBUCK - 1) ? ETOT : S[(b + 1) * NCHUNK];
    hist[t] = 0;
    __syncthreads();
    for (int j = beg + t; j < end; j += 256)
        atomicAdd(&hist[pairs[j] >> 24], 1);
    __syncthreads();
    for (int off = 1; off < 256; off <<= 1) {
        int v = hist[t];
        if (t >= off) v += hist[t - off];
        __syncthreads();
        hist[t] = v;
        __syncthreads();
    }
    int excl = (t == 0) ? 0 : hist[t - 1];
    int node = b * 256 + t;
    if (node < N_NODES) rowptr[node] = beg + excl;
    cur[t] = beg + excl;
    __syncthreads();
    for (int j = beg + t; j < end; j += 256) {
        unsigned pr = pairs[j];
        int p = atomicAdd(&cur[pr >> 24], 1);
        csr[p] = (int)(pr & 0xFFFFFFu);
    }
}

// ===== fused layer-1 attention + layer-2 projection (grid-stride) ============
// score = 0.6*(dl[s]+dr[d]) + sum (0.4*att)[t]*|xl[s][t]+xr[d][t]|
// Inner loop: packed-f32 (v_pk_add/v_pk_fma) over {col 2t, 2t+1} pairs.
// Epilogue: after the cross-sub merge ALL 64 lanes hold the merged o[], so the
// 4 subgroups compute the 4 layer-2 projection scalars (W2l/W2r x col0/col1)
// directly -> h16 intermediate (26 MB write + 26 MB re-read + k_gemm2) deleted.
__global__ void __launch_bounds__(256) k_gat1(const int* __restrict__ rowptr,
                                              const int* __restrict__ csr,
                                              const __hip_bfloat16* __restrict__ xlb,
                                              const __hip_bfloat16* __restrict__ xrb,
                                              const float* __restrict__ att,
                                              const float* __restrict__ bias,
                                              const float* __restrict__ dotsl,
                                              const float* __restrict__ dotsr,
                                              const float* __restrict__ w2a,
                                              const float* __restrict__ wb,
                                              float* __restrict__ xl2,
                                              float* __restrict__ xr2) {
    int wave = threadIdx.x >> 6, lane = threadIdx.x & 63;
    int sub = lane >> 4, li = lane & 15;
    f32x2 at2v[4];
    {
        float4 t0 = ((const float4*)att)[li * 2];
        float4 t1 = ((const float4*)att)[li * 2 + 1];
        at2v[0][0] = 0.4f * t0.x; at2v[0][1] = 0.4f * t0.y;
        at2v[1][0] = 0.4f * t0.z; at2v[1][1] = 0.4f * t0.w;
        at2v[2][0] = 0.4f * t1.x; at2v[2][1] = 0.4f * t1.y;
        at2v[3][0] = 0.4f * t1.z; at2v[3][1] = 0.4f * t1.w;
    }
    // W2 fragment for the fused layer-2 projection:
    // sub0->W2l col0, sub1->W2l col1, sub2->W2r col0, sub3->W2r col1.
    // w2a layout is linear c*2+j; lane li holds rows li*8..li*8+7.
    int col = sub & 1;
    const float* wsrc = w2a + (sub >> 1) * 256;
    float w2v[8];
#pragma unroll
    for (int k = 0; k < 8; k++) w2v[k] = wsrc[(li * 8 + k) * 2 + col];
    float b2 = wb[(sub < 2 ? WO_B2L : WO_B2R) + col];
    float* outp = (sub < 2) ? xl2 : xr2;

    for (int d = blockIdx.x * 4 + wave; d < N_NODES; d += GS_BLOCKS * 4) {
        uint4 qr = ((const uint4*)(xrb + (size_t)d * HID))[li];
        f32x2 xr2v[4]; unpack8p(qr, xr2v);
        float drd = dotsr[d];
        int beg = rowptr[d], end = rowptr[d + 1];
        int iters = (end - beg + 3) >> 2;
        float l = 0.f;
        f32x2 o2[4];
#pragma unroll
        for (int t = 0; t < 4; t++) { o2[t][0] = 0.f; o2[t][1] = 0.f; }

        int j = beg + sub;
        bool valid = j < end;
        int s = valid ? csr[j] : 0;
        uint4 q = *(const uint4*)(xlb + (size_t)s * HID + li * 8);
        float dlc = dotsl[s];

        for (int it = 0; it < iters; it++) {
            f32x2 c2[4]; unpack8p(q, c2);
            bool v = valid;
            float dle = dlc;
            j += 4;
            valid = j < end;
            int sn = valid ? csr[j] : 0;
            q = *(const uint4*)(xlb + (size_t)sn * HID + li * 8);
            dlc = dotsl[sn];

            f32x2 pa2; pa2[0] = 0.f; pa2[1] = 0.f;
#pragma unroll
            for (int t = 0; t < 4; t++) {
                f32x2 vv = pk_add(c2[t], xr2v[t]);
                f32x2 av;
                av[0] = fabsf(vv[0]); av[1] = fabsf(vv[1]);
                pk_fma_acc(pa2, at2v[t], av);
            }
            float pa = pa2[0] + pa2[1];
            pa += __shfl_xor(pa, 1);
            pa += __shfl_xor(pa, 2);
            pa += __shfl_xor(pa, 4);
            pa += __shfl_xor(pa, 8);
            float p = fmaf(0.6f, dle + drd, pa);
            float a = v ? __expf(p) : 0.f;
            l += a;
            f32x2 aa; aa[0] = a; aa[1] = a;
#pragma unroll
            for (int t = 0; t < 4; t++) pk_fma_acc(o2[t], aa, c2[t]);
        }
        // merge the 4 subgroups (all lanes end up with the full sums)
        l += __shfl_xor(l, 16);
        l += __shfl_xor(l, 32);
#pragma unroll
        for (int t = 0; t < 4; t++) {
            o2[t][0] += __shfl_xor(o2[t][0], 16);
            o2[t][1] += __shfl_xor(o2[t][1], 16);
            o2[t][0] += __shfl_xor(o2[t][0], 32);
            o2[t][1] += __shfl_xor(o2[t][1], 32);
        }
        float inv = 1.f / l;  // self-loop guarantees l > 0
        float4 bv0 = ((const float4*)bias)[li * 2];
        float4 bv1 = ((const float4*)bias)[li * 2 + 1];
        float r0 = fmaxf(fmaf(o2[0][0], inv, bv0.x), 0.f);
        float r1 = fmaxf(fmaf(o2[0][1], inv, bv0.y), 0.f);
        float r2 = fmaxf(fmaf(o2[1][0], inv, bv0.z), 0.f);
        float r3 = fmaxf(fmaf(o2[1][1], inv, bv0.w), 0.f);
        float r4 = fmaxf(fmaf(o2[2][0], inv, bv1.x), 0.f);
        float r5 = fmaxf(fmaf(o2[2][1], inv, bv1.y), 0.f);
        float r6 = fmaxf(fmaf(o2[3][0], inv, bv1.z), 0.f);
        float r7 = fmaxf(fmaf(o2[3][1], inv, bv1.w), 0.f);
        // fused layer-2 projection: dot(r, W2x[:,col]) over this sub's 16 lanes
        float dot = r0 * w2v[0];
        dot = fmaf(r1, w2v[1], dot);
        dot = fmaf(r2, w2v[2], dot);
        dot = fmaf(r3, w2v[3], dot);
        dot = fmaf(r4, w2v[4], dot);
        dot = fmaf(r5, w2v[5], dot);
        dot = fmaf(r6, w2v[6], dot);
        dot = fmaf(r7, w2v[7], dot);
        dot += __shfl_xor(dot, 1);
        dot += __shfl_xor(dot, 2);
        dot += __shfl_xor(dot, 4);
        dot += __shfl_xor(dot, 8);
        if (li == 0) outp[d * 2 + col] = dot + b2;
    }
}

// ================= fused layer-2 attention: 4 threads per dst node ===========
__global__ void __launch_bounds__(256) k_gat2(const int* __restrict__ rowptr,
                                              const int* __restrict__ csr,
                                              const float* __restrict__ xl2,
                                              const float* __restrict__ xr2,
                                              const float* __restrict__ wb,
                                              const unsigned* __restrict__ flag,
                                              void* __restrict__ dout) {
    int t = blockIdx.x * 256 + threadIdx.x;
    int d = t >> 2, part = t & 3;
    if (d >= N_NODES) return;
    float xr0 = xr2[d * 2 + 0], xr1 = xr2[d * 2 + 1];
    float at0 = wb[WO_ATT2], at1 = wb[WO_ATT2 + 1];
    int beg = rowptr[d], end = rowptr[d + 1];
    float l = 0.f, o0 = 0.f, o1 = 0.f;
    for (int j = beg + part; j < end; j += 4) {
        int s = csr[j];
        float b0 = xl2[s * 2 + 0], b1 = xl2[s * 2 + 1];
        float p = at0 * lrelu(b0 + xr0) + at1 * lrelu(b1 + xr1);
        float a = __expf(p);
        l += a;
        o0 = fmaf(a, b0, o0);
        o1 = fmaf(a, b1, o1);
    }
    // reduce the 4 parts (lanes 4d..4d+3 of one wave)
    l += __shfl_xor(l, 1);  o0 += __shfl_xor(o0, 1);  o1 += __shfl_xor(o1, 1);
    l += __shfl_xor(l, 2);  o0 += __shfl_xor(o0, 2);  o1 += __shfl_xor(o1, 2);
    if (part == 0) {
        float inv = 1.f / l;
        float v0 = fmaf(o0, inv, wb[WO_BIAS2 + 0]);
        float v1 = fmaf(o1, inv, wb[WO_BIAS2 + 1]);
        if (*flag) {
            ((__hip_bfloat16*)dout)[d * 2 + 0] = __float2bfloat16(v0);
            ((__hip_bfloat16*)dout)[d * 2 + 1] = __float2bfloat16(v1);
        } else {
            ((float*)dout)[d * 2 + 0] = v0;
            ((float*)dout)[d * 2 + 1] = v1;
        }
    }
}

extern "C" void kernel_launch(void* const* d_in, const int* in_sizes, int n_in,
                              void* d_out, int out_size, void* d_ws, size_t ws_size,
                              hipStream_t stream) {
    char* w = (char*)d_ws;
    unsigned* flag = (unsigned*)(w + (size_t)OFF_FLAG * 4);
    float* wb = (float*)(w + (size_t)OFF_W * 4);
    float* w2a = (float*)(w + (size_t)OFF_W2A * 4);
    unsigned short* wt = (unsigned short*)(w + (size_t)OFF_WT * 4);
    float* bcat = (float*)(w + (size_t)OFF_BCAT * 4);
    __hip_bfloat16* xlb = (__hip_bfloat16*)(w + (size_t)OFF_XLB * 4);
    __hip_bfloat16* xrb = (__hip_bfloat16*)(w + (size_t)OFF_XRB * 4);
    unsigned* pairs = (unsigned*)(w + (size_t)OFF_PAIRS * 4);
    int* csr = (int*)(w + (size_t)OFF_CSR * 4);
    int* rowptr = (int*)(w + (size_t)OFF_ROWPTR * 4);
    int* S = (int*)(w + (size_t)OFF_S * 4);
    float* xl2 = (float*)(w + (size_t)OFF_XL2 * 4);
    float* xr2 = (float*)(w + (size_t)OFF_XR2 * 4);
    float* dl = (float*)(w + (size_t)OFF_DL * 4);
    float* dr = (float*)(w + (size_t)OFF_DR * 4);
    const int* esrc = (const int*)d_in[1];
    const int* edst = (const int*)d_in[2];

    // ---- fused prep + per-chunk histogram ----
    k_prep_hist<<<NCHUNK + PREP_BLKS, 256, 0, stream>>>(
        edst, S, (const unsigned short*)d_in[0],
        d_in[3], d_in[4], d_in[5], d_in[6], d_in[7], d_in[8],
        d_in[9], d_in[10], d_in[11], d_in[12], d_in[13], d_in[14],
        flag, wt, bcat, wb, w2a);

    // ---- CSR scan ----
    k_pa_scan<<<1, 512, 0, stream>>>(S, rowptr);

    // ---- pairs scatter (mem/atomic-bound) overlapped with layer-1 GEMM ----
    k_scatter_gemm1<<<NCHUNK + NPAD / 64, 256, 0, stream>>>(
        esrc, edst, S, pairs, d_in[0], flag, wt, bcat,
        wb + WO_ATT1, xlb, xrb, dl, dr);

    // ---- bucket sort -> CSR ----
    k_bsort<<<NBUCK, 256, 0, stream>>>(S, pairs, rowptr, csr);

    // ---- layer-1 attention (packed-f32) + fused layer-2 projection ----
    k_gat1<<<GS_BLOCKS, 256, 0, stream>>>(rowptr, csr, xlb, xrb,
                                          wb + WO_ATT1, wb + WO_BIAS1,
                                          dl, dr, w2a, wb, xl2, xr2);

    // ---- layer-2 attention + output ----
    k_gat2<<<(4 * N_NODES + 255) / 256, 256, 0, stream>>>(rowptr, csr, xl2, xr2,
                                                          wb, flag, d_out);
}

// Round 2
// 369.984 us; speedup vs baseline: 1.0754x; 1.0332x over previous
//
#include <hip/hip_runtime.h>
#include <hip/hip_bf16.h>

#define N_NODES 100000
#define NPAD 100032                         // 64-row-aligned node count
#define N_EDGES 1600000
#define ETOT (N_EDGES + N_NODES)
#define NFEAT 165
#define KP 192                              // K padded to 32-multiple
#define HID 128
#define NCLS 2
#define NEG 0.2f

// CSR radix-build parameters
#define NBUCK 391                           // ceil(N_NODES/256); bucket = dst >> 8
#define CHUNK 16384
#define NCHUNK 104                          // ceil(ETOT/CHUNK)
#define GS_BLOCKS 2048                      // gat1 grid: 8192 waves = device capacity

typedef short bf16x8 __attribute__((ext_vector_type(8)));
typedef float f32x4 __attribute__((ext_vector_type(4)));

// ---- workspace layout (units of 4 bytes) ----
#define OFF_FLAG 0
#define OFF_W 16
// weight sub-offsets (within wb = ws + OFF_W)
#define WO_ATT1 42496
#define WO_BIAS1 42624
#define WO_W2L 42752
#define WO_B2L 43008
#define WO_W2R 43010
#define WO_B2R 43266
#define WO_ATT2 43268
#define WO_BIAS2 43270

#define OFF_XB   43392
#define OFF_W2A  OFF_XB                     // 16-B-aligned W2l[256]|W2r[256] copy
#define OFF_WT   (OFF_XB + NPAD * KP / 2)   // bf16 WT [256][192]
#define OFF_BCAT (OFF_WT + 256 * KP / 2)    // fp32 bias concat [256]
#define OFF_XLB  (OFF_BCAT + 256)           // bf16 xl rows [NPAD][128]
#define OFF_XRB  (OFF_XLB + NPAD * HID / 2) // bf16 xr rows
#define OFF_PAIRS (OFF_XRB + NPAD * HID / 2) // packed uint pairs[ETOT]
#define OFF_CSR  (OFF_PAIRS + 2 * ETOT)     // csr_src[ETOT]
#define OFF_ROWPTR (OFF_CSR + ETOT)         // rowptr[N_NODES+1]
#define OFF_S    (OFF_ROWPTR + N_NODES + 8) // per-(bucket,chunk) offsets
#define OFF_XL2  (OFF_S + NBUCK * NCHUNK + 8)
#define OFF_XR2  (OFF_XL2 + N_NODES * NCLS)
#define OFF_H    (OFF_XR2 + N_NODES * NCLS) // (unused since gemm2 fusion)
#define OFF_DL   (OFF_H + N_NODES * HID)    // fp32 dl[NPAD] = att1 . xl[n]
#define OFF_DR   (OFF_DL + NPAD)            // fp32 dr[NPAD] = att1 . xr[n]

__device__ __forceinline__ float bload16(unsigned short u) {
    return __uint_as_float(((unsigned)u) << 16);
}

// lrelu(v) = 0.6v + 0.4|v|
__device__ __forceinline__ float lrelu(float v) {
    return fmaf(0.4f, fabsf(v), 0.6f * v);
}

__device__ __forceinline__ void unpack8(uint4 q, float* f) {
    f[0] = __uint_as_float(q.x << 16); f[1] = __uint_as_float(q.x & 0xffff0000u);
    f[2] = __uint_as_float(q.y << 16); f[3] = __uint_as_float(q.y & 0xffff0000u);
    f[4] = __uint_as_float(q.z << 16); f[5] = __uint_as_float(q.z & 0xffff0000u);
    f[6] = __uint_as_float(q.w << 16); f[7] = __uint_as_float(q.w & 0xffff0000u);
}

__device__ __forceinline__ unsigned short f2b(float f) {
    __hip_bfloat16 b = __float2bfloat16(f);
    return *(unsigned short*)&b;
}

__device__ __forceinline__ unsigned pack2(float a, float b) {
    return (unsigned)f2b(a) | ((unsigned)f2b(b) << 16);
}

// wave-uniform dtype sniff: 64 halves of x; bf16 -> ~all plausible, fp32 -> ~58%
__device__ __forceinline__ unsigned detect_flag(const unsigned short* x16, int lane) {
    unsigned short hh = x16[lane];
    unsigned e = (hh >> 7) & 0xFF;
    bool pl = ((hh & 0x7FFF) == 0) || (e >= 100 && e <= 140);
    unsigned long long m = __ballot(pl);
    return (__popcll(m) >= 52) ? 1u : 0u;
}

// ---- fused: per-chunk bucket histogram (blocks 0..NCHUNK-1) + weight prep ----
#define PREP_WT 49152                       // 256*192
#define PREP_BC (PREP_WT + 256)
#define PREP_TOT (PREP_BC + 776)
#define PREP_BLKS ((PREP_TOT + 255) / 256)
__global__ void __launch_bounds__(256) k_prep_hist(
        const int* __restrict__ edst, int* __restrict__ bh,
        const unsigned short* __restrict__ x16,
        const void* W1l, const void* b1l, const void* W1r, const void* b1r,
        const void* att1, const void* bias1, const void* W2l, const void* b2l,
        const void* W2r, const void* b2r, const void* att2, const void* bias2,
        unsigned* __restrict__ flagp, unsigned short* __restrict__ wt,
        float* __restrict__ bcat, float* __restrict__ wb,
        float* __restrict__ w2a) {
    __shared__ int hist[NBUCK];
    if (blockIdx.x < NCHUNK) {
        for (int i = threadIdx.x; i < NBUCK; i += 256) hist[i] = 0;
        __syncthreads();
        int base = blockIdx.x * CHUNK;
        for (int i = threadIdx.x; i < CHUNK; i += 256) {
            int e = base + i;
            if (e >= ETOT) break;
            int d = (e < N_EDGES) ? edst[e] : (e - N_EDGES);
            atomicAdd(&hist[d >> 8], 1);
        }
        __syncthreads();
        for (int b = threadIdx.x; b < NBUCK; b += 256)
            bh[b * NCHUNK + blockIdx.x] = hist[b];
        return;
    }
    // ---- prep part ----
    int lane = threadIdx.x & 63;
    unsigned isbf = detect_flag(x16, lane);
    int i = (blockIdx.x - NCHUNK) * 256 + threadIdx.x;
    if (i == 0) *flagp = isbf;
    if (i >= PREP_TOT) return;
    if (i < PREP_WT) {
        int n = i / KP, k = i - n * KP;
        unsigned short v = 0;
        if (k < NFEAT) {
            const void* src = (n < HID) ? W1l : W1r;
            size_t off = (size_t)k * HID + (n & (HID - 1));
            v = isbf ? ((const unsigned short*)src)[off]
                     : f2b(((const float*)src)[off]);
        }
        wt[i] = v;
    } else if (i < PREP_BC) {
        int n = i - PREP_WT;
        const void* src = (n < HID) ? b1l : b1r;
        int off = n & (HID - 1);
        bcat[n] = isbf ? bload16(((const unsigned short*)src)[off])
                       : ((const float*)src)[off];
    } else {
        int j = i - PREP_BC;
        const void* src; int off; int dst;
        if      (j < 128) { src = att1;  off = j;       dst = WO_ATT1 + j; }
        else if (j < 256) { src = bias1; off = j - 128; dst = WO_BIAS1 + (j - 128); }
        else if (j < 512) { src = W2l;   off = j - 256; dst = WO_W2L + (j - 256); }
        else if (j < 514) { src = b2l;   off = j - 512; dst = WO_B2L + (j - 512); }
        else if (j < 770) { src = W2r;   off = j - 514; dst = WO_W2R + (j - 514); }
        else if (j < 772) { src = b2r;   off = j - 770; dst = WO_B2R + (j - 770); }
        else if (j < 774) { src = att2;  off = j - 772; dst = WO_ATT2 + (j - 772); }
        else              { src = bias2; off = j - 774; dst = WO_BIAS2 + (j - 774); }
        float val = isbf ? bload16(((const unsigned short*)src)[off])
                         : ((const float*)src)[off];
        wb[dst] = val;
        // 16-B-aligned copy of W2l|W2r for the fused layer-2 projection
        if (j >= 256 && j < 512) w2a[j - 256] = val;
        else if (j >= 514 && j < 770) w2a[256 + (j - 514)] = val;
    }
}

// ---- exclusive scan of the NBUCK*NCHUNK counts (uint4-vectorized) ----
__global__ void __launch_bounds__(512) k_pa_scan(int* __restrict__ S,
                                                 int* __restrict__ rowptr) {
    __shared__ int lds[512];
    const int TOT4 = (NBUCK * NCHUNK) / 4;   // 10166, exact
    int t = threadIdx.x;
    int b4 = t * 20;
    uint4* S4 = (uint4*)S;
    int sum = 0;
    for (int k = 0; k < 20; k++) {
        int i = b4 + k;
        if (i < TOT4) {
            uint4 v = S4[i];
            sum += (int)(v.x + v.y + v.z + v.w);
        }
    }
    lds[t] = sum;
    __syncthreads();
    for (int off = 1; off < 512; off <<= 1) {
        int v = lds[t];
        if (t >= off) v += lds[t - off];
        __syncthreads();
        lds[t] = v;
        __syncthreads();
    }
    int carry = (t == 0) ? 0 : lds[t - 1];
    for (int k = 0; k < 20; k++) {
        int i = b4 + k;
        if (i < TOT4) {
            uint4 v = S4[i];
            uint4 o;
            o.x = carry; carry += v.x;
            o.y = carry; carry += v.y;
            o.z = carry; carry += v.z;
            o.w = carry; carry += v.w;
            S4[i] = o;
        }
    }
    if (t == 0) rowptr[N_NODES] = ETOT;
}

// ====== fused: pairs scatter (blocks 0..NCHUNK-1) + layer-1 MFMA GEMM ========
// The scatter (memory/atomic-bound) and GEMM1 (MFMA/LDS-bound) are independent:
// scatter needs only the scanned S; GEMM1 needs only wt/bcat from prep. Fusing
// them into one grid lets the complementary work co-schedule across CUs instead
// of serializing at a kernel boundary.
#define XS_STRIDE 200
__global__ void __launch_bounds__(256) k_scatter_gemm1(
        const int* __restrict__ esrc, const int* __restrict__ edst,
        const int* __restrict__ S, unsigned* __restrict__ pairs,
        const void* __restrict__ x, const unsigned* __restrict__ flagp,
        const unsigned short* __restrict__ wt, const float* __restrict__ bcat,
        const float* __restrict__ attp,
        __hip_bfloat16* __restrict__ xlb, __hip_bfloat16* __restrict__ xrb,
        float* __restrict__ dl, float* __restrict__ dr) {
    __shared__ union {
        struct { unsigned short xs[64 * XS_STRIDE]; float dpart[4][64]; } g;
        int cur[NBUCK];
    } u;

    if (blockIdx.x < NCHUNK) {
        // ---- scatter: pairs entry = src (bits 0..16) | (dst & 255) << 24 ----
        for (int i = threadIdx.x; i < NBUCK; i += 256)
            u.cur[i] = S[i * NCHUNK + blockIdx.x];
        __syncthreads();
        int base = blockIdx.x * CHUNK;
        for (int i = threadIdx.x; i < CHUNK; i += 256) {
            int e = base + i;
            if (e >= ETOT) break;
            int s = (e < N_EDGES) ? esrc[e] : (e - N_EDGES);
            int d = (e < N_EDGES) ? edst[e] : (e - N_EDGES);
            int p = atomicAdd(&u.cur[d >> 8], 1);
            pairs[p] = (unsigned)s | ((unsigned)(d & 255) << 24);
        }
        return;
    }

    // ---- layer-1 GEMM via bf16 MFMA (C^T trick) + att-dot epilogue ----
    int tid = threadIdx.x;
    int wave = tid >> 6, lane = tid & 63;
    int quad = lane >> 4, li = lane & 15;
    int node0 = (blockIdx.x - NCHUNK) * 64;
    unsigned isbf = *flagp;
    const float* xf = (const float*)x;
    const unsigned short* x16 = (const unsigned short*)x;

    // zero pad cols [165,192)
    for (int i = tid; i < 64 * 27; i += 256) {
        int r = i / 27, c = 165 + (i - r * 27);
        u.g.xs[r * XS_STRIDE + c] = 0;
    }
    if (node0 + 64 <= N_NODES) {
        if (isbf) {
            const uint4* src = (const uint4*)(x16 + (size_t)node0 * NFEAT);
            for (int i = tid; i < 1320; i += 256) {   // 1320*8 = 64*165 halves
                uint4 v = src[i];
                int f = i * 8;
                unsigned short hh[8] = {
                    (unsigned short)(v.x & 0xffff), (unsigned short)(v.x >> 16),
                    (unsigned short)(v.y & 0xffff), (unsigned short)(v.y >> 16),
                    (unsigned short)(v.z & 0xffff), (unsigned short)(v.z >> 16),
                    (unsigned short)(v.w & 0xffff), (unsigned short)(v.w >> 16)};
#pragma unroll
                for (int t = 0; t < 8; t++) {
                    int ff = f + t, r = ff / NFEAT, c = ff - r * NFEAT;
                    u.g.xs[r * XS_STRIDE + c] = hh[t];
                }
            }
        } else {
            const float4* src = (const float4*)(xf + (size_t)node0 * NFEAT);
            for (int i = tid; i < 2640; i += 256) {   // 2640*4 = 64*165 floats
                float4 v = src[i];
                int f = i * 4;
                unsigned short hh[4] = {f2b(v.x), f2b(v.y), f2b(v.z), f2b(v.w)};
#pragma unroll
                for (int t = 0; t < 4; t++) {
                    int ff = f + t, r = ff / NFEAT, c = ff - r * NFEAT;
                    u.g.xs[r * XS_STRIDE + c] = hh[t];
                }
            }
        }
    } else {
        for (int i = tid; i < 64 * NFEAT; i += 256) {
            int r = i / NFEAT, c = i - r * NFEAT;
            int grow = node0 + r;
            unsigned short v = 0;
            if (grow < N_NODES) {
                size_t g = (size_t)grow * NFEAT + c;
                v = isbf ? x16[g] : f2b(xf[g]);
            }
            u.g.xs[r * XS_STRIDE + c] = v;
        }
    }

    bf16x8 wfrag[4][6];
#pragma unroll
    for (int q = 0; q < 4; q++) {
        int n = wave * 64 + q * 16 + li;
#pragma unroll
        for (int kk = 0; kk < 6; kk++)
            wfrag[q][kk] = *(const bf16x8*)&wt[(size_t)n * KP + kk * 32 + quad * 8];
    }
    float4 bv[4], attq4[4];
    int colbase = (wave & 1) * 64;
#pragma unroll
    for (int q = 0; q < 4; q++) {
        bv[q] = *(const float4*)&bcat[wave * 64 + q * 16 + quad * 4];
        attq4[q] = *(const float4*)&attp[colbase + q * 16 + quad * 4];
    }
    __syncthreads();

    for (int mt = 0; mt < 4; mt++) {
        bf16x8 xfrag[6];
#pragma unroll
        for (int kk = 0; kk < 6; kk++)
            xfrag[kk] = *(const bf16x8*)&u.g.xs[(mt * 16 + li) * XS_STRIDE + kk * 32 + quad * 8];
        int node = node0 + mt * 16 + li;
        __hip_bfloat16* dst = (wave < 2) ? xlb : xrb;
        float dp = 0.f;
#pragma unroll
        for (int q = 0; q < 4; q++) {
            f32x4 a = {0.f, 0.f, 0.f, 0.f};
#pragma unroll
            for (int kk = 0; kk < 6; kk++)
                a = __builtin_amdgcn_mfma_f32_16x16x32_bf16(wfrag[q][kk], xfrag[kk], a, 0, 0, 0);
            float f0 = a[0] + bv[q].x, f1 = a[1] + bv[q].y;
            float f2 = a[2] + bv[q].z, f3 = a[3] + bv[q].w;
            dp = fmaf(f0, attq4[q].x, dp);
            dp = fmaf(f1, attq4[q].y, dp);
            dp = fmaf(f2, attq4[q].z, dp);
            dp = fmaf(f3, attq4[q].w, dp);
            uint2 val = { pack2(f0, f1), pack2(f2, f3) };
            int col = colbase + q * 16 + quad * 4;
            *(uint2*)&dst[(size_t)node * HID + col] = val;
        }
        dp += __shfl_xor(dp, 16);
        dp += __shfl_xor(dp, 32);
        if (lane < 16) u.g.dpart[wave][mt * 16 + li] = dp;
    }
    __syncthreads();
    if (tid < 64)
        dl[node0 + tid] = u.g.dpart[0][tid] + u.g.dpart[1][tid];
    else if (tid < 128)
        dr[node0 + tid - 64] = u.g.dpart[2][tid - 64] + u.g.dpart[3][tid - 64];
}

__global__ void __launch_bounds__(256) k_bsort(const int* __restrict__ S,
                                               const unsigned* __restrict__ pairs,
                                               int* __restrict__ rowptr,
                                               int* __restrict__ csr) {
    __shared__ int hist[256];
    __shared__ int cur[256];
    int b = blockIdx.x, t = threadIdx.x;
    int beg = S[b * NCHUNK];
    int end = (b == NBUCK - 1) ? ETOT : S[(b + 1) * NCHUNK];
    hist[t] = 0;
    __syncthreads();
    for (int j = beg + t; j < end; j += 256)
        atomicAdd(&hist[pairs[j] >> 24], 1);
    __syncthreads();
    for (int off = 1; off < 256; off <<= 1) {
        int v = hist[t];
        if (t >= off) v += hist[t - off];
        __syncthreads();
        hist[t] = v;
        __syncthreads();
    }
    int excl = (t == 0) ? 0 : hist[t - 1];
    int node = b * 256 + t;
    if (node < N_NODES) rowptr[node] = beg + excl;
    cur[t] = beg + excl;
    __syncthreads();
    for (int j = beg + t; j < end; j += 256) {
        unsigned pr = pairs[j];
        int p = atomicAdd(&cur[pr >> 24], 1);
        csr[p] = (int)(pr & 0xFFFFFFu);
    }
}

// ===== fused layer-1 attention + layer-2 projection (grid-stride) ============
// score = 0.6*(dl[s]+dr[d]) + sum (0.4*att)[t]*|xl[s][t]+xr[d][t]|
// Inner loop is the measured-fast R9 scalar form (the round-1 packed-f32 asm
// experiment REGRESSED: VALU busy-cycles +37% from register-pair marshalling
// around the inline asm — reverted).
// Epilogue: after the cross-sub merge ALL 64 lanes hold the merged o[], so the
// 4 subgroups compute the 4 layer-2 projection scalars (W2l/W2r x col0/col1)
// directly -> h16 intermediate (26 MB write + 26 MB re-read + k_gemm2) deleted.
__global__ void __launch_bounds__(256) k_gat1(const int* __restrict__ rowptr,
                                              const int* __restrict__ csr,
                                              const __hip_bfloat16* __restrict__ xlb,
                                              const __hip_bfloat16* __restrict__ xrb,
                                              const float* __restrict__ att,
                                              const float* __restrict__ bias,
                                              const float* __restrict__ dotsl,
                                              const float* __restrict__ dotsr,
                                              const float* __restrict__ w2a,
                                              const float* __restrict__ wb,
                                              float* __restrict__ xl2,
                                              float* __restrict__ xr2) {
    int wave = threadIdx.x >> 6, lane = threadIdx.x & 63;
    int sub = lane >> 4, li = lane & 15;
    float atv[8];
    {
        float4 t0 = ((const float4*)att)[li * 2];
        float4 t1 = ((const float4*)att)[li * 2 + 1];
        atv[0] = 0.4f * t0.x; atv[1] = 0.4f * t0.y;
        atv[2] = 0.4f * t0.z; atv[3] = 0.4f * t0.w;
        atv[4] = 0.4f * t1.x; atv[5] = 0.4f * t1.y;
        atv[6] = 0.4f * t1.z; atv[7] = 0.4f * t1.w;
    }
    // loop-invariant epilogue constants, hoisted out of the d-loop
    float4 bv0 = ((const float4*)bias)[li * 2];
    float4 bv1 = ((const float4*)bias)[li * 2 + 1];
    // W2 fragment for the fused layer-2 projection:
    // sub0->W2l col0, sub1->W2l col1, sub2->W2r col0, sub3->W2r col1.
    // w2a layout is linear c*2+j; lane li holds rows li*8..li*8+7.
    int col = sub & 1;
    const float* wsrc = w2a + (sub >> 1) * 256;
    float w2v[8];
#pragma unroll
    for (int k = 0; k < 8; k++) w2v[k] = wsrc[(li * 8 + k) * 2 + col];
    float b2 = wb[(sub < 2 ? WO_B2L : WO_B2R) + col];
    float* outp = (sub < 2) ? xl2 : xr2;

    for (int d = blockIdx.x * 4 + wave; d < N_NODES; d += GS_BLOCKS * 4) {
        uint4 qr = ((const uint4*)(xrb + (size_t)d * HID))[li];
        float xrv[8]; unpack8(qr, xrv);
        float drd = dotsr[d];
        int beg = rowptr[d], end = rowptr[d + 1];
        int iters = (end - beg + 3) >> 2;
        float l = 0.f, o[8];
#pragma unroll
        for (int t = 0; t < 8; t++) o[t] = 0.f;

        int j = beg + sub;
        bool valid = j < end;
        int s = valid ? csr[j] : 0;
        uint4 q = *(const uint4*)(xlb + (size_t)s * HID + li * 8);
        float dlc = dotsl[s];

        for (int it = 0; it < iters; it++) {
            float c[8]; unpack8(q, c);
            bool v = valid;
            float dle = dlc;
            j += 4;
            valid = j < end;
            int sn = valid ? csr[j] : 0;
            q = *(const uint4*)(xlb + (size_t)sn * HID + li * 8);
            dlc = dotsl[sn];

            float pa = 0.f;
#pragma unroll
            for (int t = 0; t < 8; t++) {
                float vv = c[t] + xrv[t];
                pa = fmaf(atv[t], fabsf(vv), pa);
            }
            pa += __shfl_xor(pa, 1);
            pa += __shfl_xor(pa, 2);
            pa += __shfl_xor(pa, 4);
            pa += __shfl_xor(pa, 8);
            float p = fmaf(0.6f, dle + drd, pa);
            float a = v ? __expf(p) : 0.f;
            l += a;
#pragma unroll
            for (int t = 0; t < 8; t++) o[t] = fmaf(a, c[t], o[t]);
        }
        // merge the 4 subgroups (all lanes end up with the full sums)
        l += __shfl_xor(l, 16);
        l += __shfl_xor(l, 32);
#pragma unroll
        for (int t = 0; t < 8; t++) {
            o[t] += __shfl_xor(o[t], 16);
            o[t] += __shfl_xor(o[t], 32);
        }
        float inv = 1.f / l;  // self-loop guarantees l > 0
        float r0 = fmaxf(fmaf(o[0], inv, bv0.x), 0.f);
        float r1 = fmaxf(fmaf(o[1], inv, bv0.y), 0.f);
        float r2 = fmaxf(fmaf(o[2], inv, bv0.z), 0.f);
        float r3 = fmaxf(fmaf(o[3], inv, bv0.w), 0.f);
        float r4 = fmaxf(fmaf(o[4], inv, bv1.x), 0.f);
        float r5 = fmaxf(fmaf(o[5], inv, bv1.y), 0.f);
        float r6 = fmaxf(fmaf(o[6], inv, bv1.z), 0.f);
        float r7 = fmaxf(fmaf(o[7], inv, bv1.w), 0.f);
        // fused layer-2 projection: dot(r, W2x[:,col]) over this sub's 16 lanes
        float dot = r0 * w2v[0];
        dot = fmaf(r1, w2v[1], dot);
        dot = fmaf(r2, w2v[2], dot);
        dot = fmaf(r3, w2v[3], dot);
        dot = fmaf(r4, w2v[4], dot);
        dot = fmaf(r5, w2v[5], dot);
        dot = fmaf(r6, w2v[6], dot);
        dot = fmaf(r7, w2v[7], dot);
        dot += __shfl_xor(dot, 1);
        dot += __shfl_xor(dot, 2);
        dot += __shfl_xor(dot, 4);
        dot += __shfl_xor(dot, 8);
        if (li == 0) outp[d * 2 + col] = dot + b2;
    }
}

// ================= fused layer-2 attention: 4 threads per dst node ===========
__global__ void __launch_bounds__(256) k_gat2(const int* __restrict__ rowptr,
                                              const int* __restrict__ csr,
                                              const float* __restrict__ xl2,
                                              const float* __restrict__ xr2,
                                              const float* __restrict__ wb,
                                              const unsigned* __restrict__ flag,
                                              void* __restrict__ dout) {
    int t = blockIdx.x * 256 + threadIdx.x;
    int d = t >> 2, part = t & 3;
    if (d >= N_NODES) return;
    float xr0 = xr2[d * 2 + 0], xr1 = xr2[d * 2 + 1];
    float at0 = wb[WO_ATT2], at1 = wb[WO_ATT2 + 1];
    int beg = rowptr[d], end = rowptr[d + 1];
    float l = 0.f, o0 = 0.f, o1 = 0.f;
    for (int j = beg + part; j < end; j += 4) {
        int s = csr[j];
        float b0 = xl2[s * 2 + 0], b1 = xl2[s * 2 + 1];
        float p = at0 * lrelu(b0 + xr0) + at1 * lrelu(b1 + xr1);
        float a = __expf(p);
        l += a;
        o0 = fmaf(a, b0, o0);
        o1 = fmaf(a, b1, o1);
    }
    // reduce the 4 parts (lanes 4d..4d+3 of one wave)
    l += __shfl_xor(l, 1);  o0 += __shfl_xor(o0, 1);  o1 += __shfl_xor(o1, 1);
    l += __shfl_xor(l, 2);  o0 += __shfl_xor(o0, 2);  o1 += __shfl_xor(o1, 2);
    if (part == 0) {
        float inv = 1.f / l;
        float v0 = fmaf(o0, inv, wb[WO_BIAS2 + 0]);
        float v1 = fmaf(o1, inv, wb[WO_BIAS2 + 1]);
        if (*flag) {
            ((__hip_bfloat16*)dout)[d * 2 + 0] = __float2bfloat16(v0);
            ((__hip_bfloat16*)dout)[d * 2 + 1] = __float2bfloat16(v1);
        } else {
            ((float*)dout)[d * 2 + 0] = v0;
            ((float*)dout)[d * 2 + 1] = v1;
        }
    }
}

extern "C" void kernel_launch(void* const* d_in, const int* in_sizes, int n_in,
                              void* d_out, int out_size, void* d_ws, size_t ws_size,
                              hipStream_t stream) {
    char* w = (char*)d_ws;
    unsigned* flag = (unsigned*)(w + (size_t)OFF_FLAG * 4);
    float* wb = (float*)(w + (size_t)OFF_W * 4);
    float* w2a = (float*)(w + (size_t)OFF_W2A * 4);
    unsigned short* wt = (unsigned short*)(w + (size_t)OFF_WT * 4);
    float* bcat = (float*)(w + (size_t)OFF_BCAT * 4);
    __hip_bfloat16* xlb = (__hip_bfloat16*)(w + (size_t)OFF_XLB * 4);
    __hip_bfloat16* xrb = (__hip_bfloat16*)(w + (size_t)OFF_XRB * 4);
    unsigned* pairs = (unsigned*)(w + (size_t)OFF_PAIRS * 4);
    int* csr = (int*)(w + (size_t)OFF_CSR * 4);
    int* rowptr = (int*)(w + (size_t)OFF_ROWPTR * 4);
    int* S = (int*)(w + (size_t)OFF_S * 4);
    float* xl2 = (float*)(w + (size_t)OFF_XL2 * 4);
    float* xr2 = (float*)(w + (size_t)OFF_XR2 * 4);
    float* dl = (float*)(w + (size_t)OFF_DL * 4);
    float* dr = (float*)(w + (size_t)OFF_DR * 4);
    const int* esrc = (const int*)d_in[1];
    const int* edst = (const int*)d_in[2];

    // ---- fused prep + per-chunk histogram ----
    k_prep_hist<<<NCHUNK + PREP_BLKS, 256, 0, stream>>>(
        edst, S, (const unsigned short*)d_in[0],
        d_in[3], d_in[4], d_in[5], d_in[6], d_in[7], d_in[8],
        d_in[9], d_in[10], d_in[11], d_in[12], d_in[13], d_in[14],
        flag, wt, bcat, wb, w2a);

    // ---- CSR scan ----
    k_pa_scan<<<1, 512, 0, stream>>>(S, rowptr);

    // ---- pairs scatter (mem/atomic-bound) overlapped with layer-1 GEMM ----
    k_scatter_gemm1<<<NCHUNK + NPAD / 64, 256, 0, stream>>>(
        esrc, edst, S, pairs, d_in[0], flag, wt, bcat,
        wb + WO_ATT1, xlb, xrb, dl, dr);

    // ---- bucket sort -> CSR ----
    k_bsort<<<NBUCK, 256, 0, stream>>>(S, pairs, rowptr, csr);

    // ---- layer-1 attention (R9 scalar loop) + fused layer-2 projection ----
    k_gat1<<<GS_BLOCKS, 256, 0, stream>>>(rowptr, csr, xlb, xrb,
                                          wb + WO_ATT1, wb + WO_BIAS1,
                                          dl, dr, w2a, wb, xl2, xr2);

    // ---- layer-2 attention + output ----
    k_gat2<<<(4 * N_NODES + 255) / 256, 256, 0, stream>>>(rowptr, csr, xl2, xr2,
                                                          wb, flag, d_out);
}